// Round 5
// baseline (440.575 us; speedup 1.0000x reference)
//
#include <hip/hip_runtime.h>
#include <hip/hip_fp16.h>

#define NROUTES 1152
#define NCAPS   10
#define INCH    8
#define OUTCH   16
#define NBATCH  512
#define NITER   3
#define TPB     576          // 9 waves
#define RPT     2            // routes per thread: 576*2 = 1152
#define NB      2            // batches per block
#define NWAVES  (TPB / 64)

// u_hat in LDS as fp16 (packed half4 in uint4): 73.7 KiB -> 2 blocks/CU
// (round 4 at fp32/148KiB was 1 block/CU, 27% occupancy, latency-bound).
// Registers hold only ~60 values -> no spill (rounds 1-3 lesson).
__global__ __launch_bounds__(TPB, 2)
void caps_route_kernel(const float* __restrict__ X,     // (R, B, I)
                       const float* __restrict__ W,     // (R, C, O, I)
                       float* __restrict__ OUT)         // (B, C, O)
{
    const int t    = threadIdx.x;
    const int wid  = t >> 6;
    const int lane = t & 63;
    const int c    = blockIdx.x / (NBATCH / NB);   // c-major: same-c blocks adjacent
    const int b0   = (blockIdx.x % (NBATCH / NB)) * NB;

    __shared__ uint4  uh[NB][RPT * 2][TPB];   // 2*4*576*16B = 73.7 KiB, fp16 x8 per entry
    __shared__ float  red[NWAVES][20];        // per-wave partials: [0..15]=S, [16]=Z
    __shared__ float  fin[20];                // block-reduced totals
    __shared__ float  redmax[NWAVES][NB];

    float bij[NB][RPT];                       // routing logits (4 regs)

    // ---------------- u_hat = W[r,c] @ x[r,b] -> LDS (fp16) ----------------
    #pragma unroll
    for (int j = 0; j < RPT; ++j) {
        const int r = t * RPT + j;
        const float* xp = X + ((size_t)r * NBATCH + b0) * INCH;  // 2 batches = 16 contiguous floats
        float4 xa = *reinterpret_cast<const float4*>(xp);
        float4 xb = *reinterpret_cast<const float4*>(xp + 4);
        float4 xc = *reinterpret_cast<const float4*>(xp + 8);
        float4 xd = *reinterpret_cast<const float4*>(xp + 12);
        float xv[NB][INCH] = {
            { xa.x, xa.y, xa.z, xa.w, xb.x, xb.y, xb.z, xb.w },
            { xc.x, xc.y, xc.z, xc.w, xd.x, xd.y, xd.z, xd.w } };
        const float* wp = W + ((size_t)r * NCAPS + c) * (OUTCH * INCH);
        #pragma unroll
        for (int h = 0; h < 2; ++h) {              // two 8-wide output halves
            float a[NB][8];
            #pragma unroll
            for (int oi = 0; oi < 8; ++oi) {
                const int o = h * 8 + oi;
                float4 w0 = *reinterpret_cast<const float4*>(wp + o * INCH);
                float4 w1 = *reinterpret_cast<const float4*>(wp + o * INCH + 4);
                #pragma unroll
                for (int nb = 0; nb < NB; ++nb) {
                    float acc = w0.x * xv[nb][0];
                    acc = fmaf(w0.y, xv[nb][1], acc);
                    acc = fmaf(w0.z, xv[nb][2], acc);
                    acc = fmaf(w0.w, xv[nb][3], acc);
                    acc = fmaf(w1.x, xv[nb][4], acc);
                    acc = fmaf(w1.y, xv[nb][5], acc);
                    acc = fmaf(w1.z, xv[nb][6], acc);
                    acc = fmaf(w1.w, xv[nb][7], acc);
                    a[nb][oi] = acc;
                }
            }
            #pragma unroll
            for (int nb = 0; nb < NB; ++nb) {
                uint4 pk;
                __half2* ph = reinterpret_cast<__half2*>(&pk);
                #pragma unroll
                for (int k = 0; k < 4; ++k)
                    ph[k] = __float22half2_rn(make_float2(a[nb][2 * k], a[nb][2 * k + 1]));
                uh[nb][j * 2 + h][t] = pk;
            }
        }
    }

    #pragma unroll
    for (int nb = 0; nb < NB; ++nb)
        #pragma unroll
        for (int j = 0; j < RPT; ++j)
            bij[nb][j] = 0.0f;

    // ---------------- dynamic routing ----------------
    #pragma unroll
    for (int it = 0; it < NITER; ++it) {
        // ---- block max of bij per nb (stable softmax) ----
        float mx[NB];
        #pragma unroll
        for (int nb = 0; nb < NB; ++nb) {
            float m = bij[nb][0];
            #pragma unroll
            for (int j = 1; j < RPT; ++j) m = fmaxf(m, bij[nb][j]);
            mx[nb] = m;
        }
        #pragma unroll
        for (int sh = 1; sh <= 32; sh <<= 1) {
            #pragma unroll
            for (int nb = 0; nb < NB; ++nb)
                mx[nb] = fmaxf(mx[nb], __shfl_xor(mx[nb], sh));
        }
        if (lane == 0) {
            #pragma unroll
            for (int nb = 0; nb < NB; ++nb) redmax[wid][nb] = mx[nb];
        }
        __syncthreads();
        #pragma unroll
        for (int nb = 0; nb < NB; ++nb) {
            float m = redmax[0][nb];
            #pragma unroll
            for (int w = 1; w < NWAVES; ++w) m = fmaxf(m, redmax[w][nb]);
            mx[nb] = m;
        }

        // ---- sequential per-nb: reduce S,Z -> squash -> b-update ----
        #pragma unroll
        for (int nb = 0; nb < NB; ++nb) {
            float S[OUTCH];
            float Z = 0.0f;
            #pragma unroll
            for (int o = 0; o < OUTCH; ++o) S[o] = 0.0f;
            #pragma unroll
            for (int j = 0; j < RPT; ++j) {
                float ev = __expf(bij[nb][j] - mx[nb]);
                Z += ev;
                #pragma unroll
                for (int h = 0; h < 2; ++h) {
                    uint4 pk = uh[nb][j * 2 + h][t];
                    const __half2* ph = reinterpret_cast<const __half2*>(&pk);
                    #pragma unroll
                    for (int k = 0; k < 4; ++k) {
                        float2 f = __half22float2(ph[k]);
                        S[h * 8 + 2 * k]     = fmaf(ev, f.x, S[h * 8 + 2 * k]);
                        S[h * 8 + 2 * k + 1] = fmaf(ev, f.y, S[h * 8 + 2 * k + 1]);
                    }
                }
            }

            // wave butterfly reduce {S[16], Z}
            #pragma unroll
            for (int sh = 1; sh <= 32; sh <<= 1) {
                Z += __shfl_xor(Z, sh);
                #pragma unroll
                for (int o = 0; o < OUTCH; ++o)
                    S[o] += __shfl_xor(S[o], sh);
            }
            if (lane == 0) {
                #pragma unroll
                for (int o = 0; o < OUTCH; ++o) red[wid][o] = S[o];
                red[wid][16] = Z;
            }
            __syncthreads();   // B1

            if (t < 17) {
                float s = red[0][t];
                #pragma unroll
                for (int w = 1; w < NWAVES; ++w) s += red[w][t];
                fin[t] = s;
            }
            __syncthreads();   // B2

            // squash (redundant per thread; broadcast from LDS)
            float v[OUTCH];
            {
                float rZ = 1.0f / fin[16];
                float n2 = 0.0f;
                #pragma unroll
                for (int o = 0; o < OUTCH; ++o) {
                    float sv = fin[o] * rZ;
                    v[o] = sv;
                    n2 = fmaf(sv, sv, n2);
                }
                float sc = sqrtf(n2) / (1.0f + n2);
                #pragma unroll
                for (int o = 0; o < OUTCH; ++o) v[o] *= sc;
            }

            if (it < NITER - 1) {
                // logit update: b += <u, v>
                #pragma unroll
                for (int j = 0; j < RPT; ++j) {
                    float d = 0.0f;
                    #pragma unroll
                    for (int h = 0; h < 2; ++h) {
                        uint4 pk = uh[nb][j * 2 + h][t];
                        const __half2* ph = reinterpret_cast<const __half2*>(&pk);
                        #pragma unroll
                        for (int k = 0; k < 4; ++k) {
                            float2 f = __half22float2(ph[k]);
                            d = fmaf(f.x, v[h * 8 + 2 * k], d);
                            d = fmaf(f.y, v[h * 8 + 2 * k + 1], d);
                        }
                    }
                    bij[nb][j] += d;
                }
            } else if (t == 0) {
                float* op = OUT + ((size_t)(b0 + nb) * NCAPS + c) * OUTCH;
                #pragma unroll
                for (int o = 0; o < OUTCH; o += 4)
                    *reinterpret_cast<float4*>(op + o) =
                        make_float4(v[o], v[o + 1], v[o + 2], v[o + 3]);
            }
            // red/fin reuse across nb/it is barrier-separated by B1/B2 above.
        }
    }
}

extern "C" void kernel_launch(void* const* d_in, const int* in_sizes, int n_in,
                              void* d_out, int out_size, void* d_ws, size_t ws_size,
                              hipStream_t stream) {
    const float* X = (const float*)d_in[0];            // (1152, 512, 8)
    const float* W = (const float*)d_in[1];            // (1152, 10, 16, 8)
    float* OUT     = (float*)d_out;                    // (512, 10, 16)
    dim3 grid(NCAPS * (NBATCH / NB));                  // 2560 workgroups, c-major
    caps_route_kernel<<<grid, dim3(TPB), 0, stream>>>(X, W, OUT);
}

// Round 6
// 293.402 us; speedup vs baseline: 1.5016x; 1.5016x over previous
//
#include <hip/hip_runtime.h>
#include <hip/hip_fp16.h>

#define NROUTES 1152
#define NCAPS   10
#define INCH    8
#define OUTCH   16
#define NBATCH  512
#define NITER   3
#define TPB     576          // 9 waves
#define RPT     2            // routes per thread: 576*2 = 1152
#define NB      4            // batches per block (amortize W c-slice read)
#define NWAVES  (TPB / 64)

// NB=4: W c-slice (590 KB) read once per 4 batches -> per-CU L2 traffic 6.6->3.7 MB
// (rounds 4/5 measured the 44us/block per-CU L2-read wall at NB=2).
// uh in LDS fp16: 147 KiB. Routing: no max-pass (|b|<~30, exp safe), iter-1 uniform
// (no exp), b-update+exp+S fused into ONE uh pass -> 3 uh passes instead of 5.
// nb handled in pairs, pair-OUTER loop (independent problems) -> live regs ~100.
__global__ __launch_bounds__(TPB, 2)
void caps_route_kernel(const float* __restrict__ X,     // (R, B, I)
                       const float* __restrict__ W,     // (R, C, O, I)
                       float* __restrict__ OUT)         // (B, C, O)
{
    const int t    = threadIdx.x;
    const int wid  = t >> 6;
    const int lane = t & 63;
    const int c    = blockIdx.x / (NBATCH / NB);   // c-major: same-c blocks adjacent
    const int b0   = (blockIdx.x % (NBATCH / NB)) * NB;

    __shared__ uint4 uh[NB][RPT * 2][TPB];   // 4*4*576*16B = 147456 B, fp16 x8
    __shared__ float red[NWAVES][2][17];     // per-wave partials for a pair
    __shared__ float fin[2][17];             // block totals for a pair

    // ---------------- staging: u_hat = W[r,c] @ x[r,b] -> LDS fp16 ----------------
    #pragma unroll
    for (int j = 0; j < RPT; ++j) {
        const int r = t * RPT + j;
        const float* xp = X + ((size_t)r * NBATCH + b0) * INCH;  // 4 batches = 32 contiguous floats
        float xv[NB][INCH];
        #pragma unroll
        for (int nb = 0; nb < NB; ++nb) {
            float4 a0 = *reinterpret_cast<const float4*>(xp + nb * INCH);
            float4 a1 = *reinterpret_cast<const float4*>(xp + nb * INCH + 4);
            xv[nb][0] = a0.x; xv[nb][1] = a0.y; xv[nb][2] = a0.z; xv[nb][3] = a0.w;
            xv[nb][4] = a1.x; xv[nb][5] = a1.y; xv[nb][6] = a1.z; xv[nb][7] = a1.w;
        }
        const float* wp = W + ((size_t)r * NCAPS + c) * (OUTCH * INCH);
        #pragma unroll
        for (int h = 0; h < 2; ++h) {              // two 8-wide output halves
            float a[NB][8];
            #pragma unroll
            for (int oi = 0; oi < 8; ++oi) {
                const int o = h * 8 + oi;
                float4 w0 = *reinterpret_cast<const float4*>(wp + o * INCH);
                float4 w1 = *reinterpret_cast<const float4*>(wp + o * INCH + 4);
                #pragma unroll
                for (int nb = 0; nb < NB; ++nb) {
                    float acc = w0.x * xv[nb][0];
                    acc = fmaf(w0.y, xv[nb][1], acc);
                    acc = fmaf(w0.z, xv[nb][2], acc);
                    acc = fmaf(w0.w, xv[nb][3], acc);
                    acc = fmaf(w1.x, xv[nb][4], acc);
                    acc = fmaf(w1.y, xv[nb][5], acc);
                    acc = fmaf(w1.z, xv[nb][6], acc);
                    acc = fmaf(w1.w, xv[nb][7], acc);
                    a[nb][oi] = acc;
                }
            }
            #pragma unroll
            for (int nb = 0; nb < NB; ++nb) {
                uint4 pk;
                __half2* ph = reinterpret_cast<__half2*>(&pk);
                #pragma unroll
                for (int k = 0; k < 4; ++k)
                    ph[k] = __float22half2_rn(make_float2(a[nb][2 * k], a[nb][2 * k + 1]));
                uh[nb][j * 2 + h][t] = pk;
            }
        }
    }
    // no barrier: each thread reads only its own uh[.][.][t] entries.

    // ---------------- routing: pairs outer (independent problems) ----------------
    #pragma unroll
    for (int p = 0; p < NB / 2; ++p) {
        const int nA = 2 * p, nB_ = 2 * p + 1;
        float v0[OUTCH], v1[OUTCH];       // v from previous iteration
        float bA[RPT], bB[RPT];           // routing logits
        #pragma unroll
        for (int j = 0; j < RPT; ++j) { bA[j] = 0.0f; bB[j] = 0.0f; }

        #pragma unroll
        for (int it = 0; it < NITER; ++it) {
            float S0[OUTCH], S1[OUTCH];
            float Z0 = 0.0f, Z1 = 0.0f;
            #pragma unroll
            for (int o = 0; o < OUTCH; ++o) { S0[o] = 0.0f; S1[o] = 0.0f; }

            // ---- fused pass: (b-update + exp) + S accumulate, ONE uh read ----
            #pragma unroll
            for (int j = 0; j < RPT; ++j) {
                float uA[OUTCH], uB[OUTCH];
                {
                    uint4 pk0 = uh[nA][j * 2][t];
                    uint4 pk1 = uh[nA][j * 2 + 1][t];
                    const __half2* p0 = reinterpret_cast<const __half2*>(&pk0);
                    const __half2* p1 = reinterpret_cast<const __half2*>(&pk1);
                    #pragma unroll
                    for (int k = 0; k < 4; ++k) {
                        float2 f = __half22float2(p0[k]);
                        uA[2 * k] = f.x; uA[2 * k + 1] = f.y;
                        float2 g = __half22float2(p1[k]);
                        uA[8 + 2 * k] = g.x; uA[8 + 2 * k + 1] = g.y;
                    }
                    uint4 qk0 = uh[nB_][j * 2][t];
                    uint4 qk1 = uh[nB_][j * 2 + 1][t];
                    const __half2* q0 = reinterpret_cast<const __half2*>(&qk0);
                    const __half2* q1 = reinterpret_cast<const __half2*>(&qk1);
                    #pragma unroll
                    for (int k = 0; k < 4; ++k) {
                        float2 f = __half22float2(q0[k]);
                        uB[2 * k] = f.x; uB[2 * k + 1] = f.y;
                        float2 g = __half22float2(q1[k]);
                        uB[8 + 2 * k] = g.x; uB[8 + 2 * k + 1] = g.y;
                    }
                }
                if (it == 0) {
                    // uniform c (b=0): S = sum u, Z = 1152 (constant)
                    #pragma unroll
                    for (int o = 0; o < OUTCH; ++o) { S0[o] += uA[o]; S1[o] += uB[o]; }
                } else {
                    float dA = 0.0f, dB = 0.0f;
                    #pragma unroll
                    for (int o = 0; o < OUTCH; ++o) {
                        dA = fmaf(uA[o], v0[o], dA);
                        dB = fmaf(uB[o], v1[o], dB);
                    }
                    bA[j] += dA; bB[j] += dB;
                    float eA = __expf(bA[j]);
                    float eB = __expf(bB[j]);
                    Z0 += eA; Z1 += eB;
                    #pragma unroll
                    for (int o = 0; o < OUTCH; ++o) {
                        S0[o] = fmaf(eA, uA[o], S0[o]);
                        S1[o] = fmaf(eB, uB[o], S1[o]);
                    }
                }
            }

            // ---- wave butterfly reduce {S0,S1,Z0,Z1} (2x ILP) ----
            #pragma unroll
            for (int sh = 1; sh <= 32; sh <<= 1) {
                Z0 += __shfl_xor(Z0, sh);
                Z1 += __shfl_xor(Z1, sh);
                #pragma unroll
                for (int o = 0; o < OUTCH; ++o) {
                    S0[o] += __shfl_xor(S0[o], sh);
                    S1[o] += __shfl_xor(S1[o], sh);
                }
            }
            if (lane == 0) {
                #pragma unroll
                for (int o = 0; o < OUTCH; ++o) {
                    red[wid][0][o] = S0[o];
                    red[wid][1][o] = S1[o];
                }
                red[wid][0][16] = Z0;
                red[wid][1][16] = Z1;
            }
            __syncthreads();   // B1

            if (t < 34) {
                const int nb = t / 17, k = t % 17;
                float s = red[0][nb][k];
                #pragma unroll
                for (int w = 1; w < NWAVES; ++w) s += red[w][nb][k];
                fin[nb][k] = s;
            }
            __syncthreads();   // B2

            // ---- squash both (redundant per thread; broadcast from LDS) ----
            {
                float rZA = (it == 0) ? (1.0f / 1152.0f) : (1.0f / fin[0][16]);
                float rZB = (it == 0) ? (1.0f / 1152.0f) : (1.0f / fin[1][16]);
                float n2A = 0.0f, n2B = 0.0f;
                #pragma unroll
                for (int o = 0; o < OUTCH; ++o) {
                    float sA = fin[0][o] * rZA;
                    float sB = fin[1][o] * rZB;
                    v0[o] = sA; n2A = fmaf(sA, sA, n2A);
                    v1[o] = sB; n2B = fmaf(sB, sB, n2B);
                }
                float scA = sqrtf(n2A) / (1.0f + n2A);
                float scB = sqrtf(n2B) / (1.0f + n2B);
                #pragma unroll
                for (int o = 0; o < OUTCH; ++o) { v0[o] *= scA; v1[o] *= scB; }
            }
            // fin/red reuse next iter is ordered by next iter's B1 (readers here
            // finish before any thread reaches it); no extra barrier.
        }

        if (t == 0) {
            float* opA = OUT + ((size_t)(b0 + nA) * NCAPS + c) * OUTCH;
            float* opB = OUT + ((size_t)(b0 + nB_) * NCAPS + c) * OUTCH;
            #pragma unroll
            for (int o = 0; o < OUTCH; o += 4) {
                *reinterpret_cast<float4*>(opA + o) =
                    make_float4(v0[o], v0[o + 1], v0[o + 2], v0[o + 3]);
                *reinterpret_cast<float4*>(opB + o) =
                    make_float4(v1[o], v1[o + 1], v1[o + 2], v1[o + 3]);
            }
        }
        __syncthreads();   // separate red/fin use across pairs
    }
}

extern "C" void kernel_launch(void* const* d_in, const int* in_sizes, int n_in,
                              void* d_out, int out_size, void* d_ws, size_t ws_size,
                              hipStream_t stream) {
    const float* X = (const float*)d_in[0];            // (1152, 512, 8)
    const float* W = (const float*)d_in[1];            // (1152, 10, 16, 8)
    float* OUT     = (float*)d_out;                    // (512, 10, 16)
    dim3 grid(NCAPS * (NBATCH / NB));                  // 1280 workgroups, c-major
    caps_route_kernel<<<grid, dim3(TPB), 0, stream>>>(X, W, OUT);
}

// Round 7
// 186.897 us; speedup vs baseline: 2.3573x; 1.5699x over previous
//
#include <hip/hip_runtime.h>
#include <hip/hip_fp16.h>

#define NROUTES 1152
#define NCAPS   10
#define INCH    8
#define OUTCH   16
#define NBATCH  512
#define NITER   3
#define TPB     576          // 9 waves
#define RPT     2            // routes per thread: 576*2 = 1152
#define NB      4            // batches per block (amortize W c-slice read)
#define NWAVES  (TPB / 64)

// Round 7: scatter-halving butterfly reduction. Round 6's full butterfly was
// 1224 ds_bpermute/thread (~27us/slot on the single DS pipe); scatter version
// is ~290. Everything else (NB=4, fp16 uh in LDS, fused b-update+exp+S pass,
// iter-0 uniform softmax) unchanged from round 6.
__global__ __launch_bounds__(TPB, 2)
void caps_route_kernel(const float* __restrict__ X,     // (R, B, I)
                       const float* __restrict__ W,     // (R, C, O, I)
                       float* __restrict__ OUT)         // (B, C, O)
{
    const int t    = threadIdx.x;
    const int wid  = t >> 6;
    const int lane = t & 63;
    const int c    = blockIdx.x / (NBATCH / NB);   // c-major: same-c blocks adjacent
    const int b0   = (blockIdx.x % (NBATCH / NB)) * NB;

    __shared__ uint4 uh[NB][RPT * 2][TPB];   // 4*4*576*16B = 147456 B, fp16 x8
    __shared__ float red[NWAVES][2][17];     // per-wave totals for a pair
    __shared__ float fin[2][17];             // block totals for a pair

    // ---------------- staging: u_hat = W[r,c] @ x[r,b] -> LDS fp16 ----------------
    #pragma unroll
    for (int j = 0; j < RPT; ++j) {
        const int r = t * RPT + j;
        const float* xp = X + ((size_t)r * NBATCH + b0) * INCH;  // 4 batches = 32 contiguous floats
        float xv[NB][INCH];
        #pragma unroll
        for (int nb = 0; nb < NB; ++nb) {
            float4 a0 = *reinterpret_cast<const float4*>(xp + nb * INCH);
            float4 a1 = *reinterpret_cast<const float4*>(xp + nb * INCH + 4);
            xv[nb][0] = a0.x; xv[nb][1] = a0.y; xv[nb][2] = a0.z; xv[nb][3] = a0.w;
            xv[nb][4] = a1.x; xv[nb][5] = a1.y; xv[nb][6] = a1.z; xv[nb][7] = a1.w;
        }
        const float* wp = W + ((size_t)r * NCAPS + c) * (OUTCH * INCH);
        #pragma unroll
        for (int h = 0; h < 2; ++h) {              // two 8-wide output halves
            float a[NB][8];
            #pragma unroll
            for (int oi = 0; oi < 8; ++oi) {
                const int o = h * 8 + oi;
                float4 w0 = *reinterpret_cast<const float4*>(wp + o * INCH);
                float4 w1 = *reinterpret_cast<const float4*>(wp + o * INCH + 4);
                #pragma unroll
                for (int nb = 0; nb < NB; ++nb) {
                    float acc = w0.x * xv[nb][0];
                    acc = fmaf(w0.y, xv[nb][1], acc);
                    acc = fmaf(w0.z, xv[nb][2], acc);
                    acc = fmaf(w0.w, xv[nb][3], acc);
                    acc = fmaf(w1.x, xv[nb][4], acc);
                    acc = fmaf(w1.y, xv[nb][5], acc);
                    acc = fmaf(w1.z, xv[nb][6], acc);
                    acc = fmaf(w1.w, xv[nb][7], acc);
                    a[nb][oi] = acc;
                }
            }
            #pragma unroll
            for (int nb = 0; nb < NB; ++nb) {
                uint4 pk;
                __half2* ph = reinterpret_cast<__half2*>(&pk);
                #pragma unroll
                for (int k = 0; k < 4; ++k)
                    ph[k] = __float22half2_rn(make_float2(a[nb][2 * k], a[nb][2 * k + 1]));
                uh[nb][j * 2 + h][t] = pk;
            }
        }
    }
    // no barrier: each thread reads only its own uh[.][.][t] entries.

    // ---------------- routing: pairs outer (independent problems) ----------------
    #pragma unroll
    for (int p = 0; p < NB / 2; ++p) {
        const int nA = 2 * p, nB_ = 2 * p + 1;
        float v0[OUTCH], v1[OUTCH];       // v from previous iteration
        float bA[RPT], bB[RPT];           // routing logits
        #pragma unroll
        for (int j = 0; j < RPT; ++j) { bA[j] = 0.0f; bB[j] = 0.0f; }

        #pragma unroll
        for (int it = 0; it < NITER; ++it) {
            float S0[OUTCH], S1[OUTCH];
            float Z0 = 0.0f, Z1 = 0.0f;
            #pragma unroll
            for (int o = 0; o < OUTCH; ++o) { S0[o] = 0.0f; S1[o] = 0.0f; }

            // ---- fused pass: (b-update + exp) + S accumulate, ONE uh read ----
            #pragma unroll
            for (int j = 0; j < RPT; ++j) {
                float uA[OUTCH], uB[OUTCH];
                {
                    uint4 pk0 = uh[nA][j * 2][t];
                    uint4 pk1 = uh[nA][j * 2 + 1][t];
                    const __half2* p0 = reinterpret_cast<const __half2*>(&pk0);
                    const __half2* p1 = reinterpret_cast<const __half2*>(&pk1);
                    #pragma unroll
                    for (int k = 0; k < 4; ++k) {
                        float2 f = __half22float2(p0[k]);
                        uA[2 * k] = f.x; uA[2 * k + 1] = f.y;
                        float2 g = __half22float2(p1[k]);
                        uA[8 + 2 * k] = g.x; uA[8 + 2 * k + 1] = g.y;
                    }
                    uint4 qk0 = uh[nB_][j * 2][t];
                    uint4 qk1 = uh[nB_][j * 2 + 1][t];
                    const __half2* q0 = reinterpret_cast<const __half2*>(&qk0);
                    const __half2* q1 = reinterpret_cast<const __half2*>(&qk1);
                    #pragma unroll
                    for (int k = 0; k < 4; ++k) {
                        float2 f = __half22float2(q0[k]);
                        uB[2 * k] = f.x; uB[2 * k + 1] = f.y;
                        float2 g = __half22float2(q1[k]);
                        uB[8 + 2 * k] = g.x; uB[8 + 2 * k + 1] = g.y;
                    }
                }
                if (it == 0) {
                    // uniform c (b=0): S = sum u, Z = 1152 (constant)
                    #pragma unroll
                    for (int o = 0; o < OUTCH; ++o) { S0[o] += uA[o]; S1[o] += uB[o]; }
                } else {
                    float dA = 0.0f, dB = 0.0f;
                    #pragma unroll
                    for (int o = 0; o < OUTCH; ++o) {
                        dA = fmaf(uA[o], v0[o], dA);
                        dB = fmaf(uB[o], v1[o], dB);
                    }
                    bA[j] += dA; bB[j] += dB;
                    float eA = __expf(bA[j]);
                    float eB = __expf(bB[j]);
                    Z0 += eA; Z1 += eB;
                    #pragma unroll
                    for (int o = 0; o < OUTCH; ++o) {
                        S0[o] = fmaf(eA, uA[o], S0[o]);
                        S1[o] = fmaf(eB, uB[o], S1[o]);
                    }
                }
            }

            // ---- scatter-halving wave reduce: 17 shuffles per S[16] ----
            float sA, sB;
            {
                float a8[8], b8[8];
                {
                    const int bit = lane & 1;
                    #pragma unroll
                    for (int i = 0; i < 8; ++i) {
                        a8[i] = (bit ? S0[i + 8] : S0[i]) +
                                __shfl_xor(bit ? S0[i] : S0[i + 8], 1);
                        b8[i] = (bit ? S1[i + 8] : S1[i]) +
                                __shfl_xor(bit ? S1[i] : S1[i + 8], 1);
                    }
                }
                float a4[4], b4[4];
                {
                    const int bit = lane & 2;
                    #pragma unroll
                    for (int i = 0; i < 4; ++i) {
                        a4[i] = (bit ? a8[i + 4] : a8[i]) +
                                __shfl_xor(bit ? a8[i] : a8[i + 4], 2);
                        b4[i] = (bit ? b8[i + 4] : b8[i]) +
                                __shfl_xor(bit ? b8[i] : b8[i + 4], 2);
                    }
                }
                float a2[2], b2[2];
                {
                    const int bit = lane & 4;
                    #pragma unroll
                    for (int i = 0; i < 2; ++i) {
                        a2[i] = (bit ? a4[i + 2] : a4[i]) +
                                __shfl_xor(bit ? a4[i] : a4[i + 2], 4);
                        b2[i] = (bit ? b4[i + 2] : b4[i]) +
                                __shfl_xor(bit ? b4[i] : b4[i + 2], 4);
                    }
                }
                {
                    const int bit = lane & 8;
                    sA = (bit ? a2[1] : a2[0]) + __shfl_xor(bit ? a2[0] : a2[1], 8);
                    sB = (bit ? b2[1] : b2[0]) + __shfl_xor(bit ? b2[0] : b2[1], 8);
                }
                sA += __shfl_xor(sA, 16);  sA += __shfl_xor(sA, 32);
                sB += __shfl_xor(sB, 16);  sB += __shfl_xor(sB, 32);
            }
            if (it > 0) {   // Z is the constant 1152 on iter 0
                #pragma unroll
                for (int sh = 1; sh <= 32; sh <<= 1) {
                    Z0 += __shfl_xor(Z0, sh);
                    Z1 += __shfl_xor(Z1, sh);
                }
            }

            // lane l<16 holds wave total for o = bitrev4(l)
            if (lane < 16) {
                const int o = ((lane & 1) << 3) | ((lane & 2) << 1) |
                              ((lane & 4) >> 1) | ((lane & 8) >> 3);
                red[wid][0][o] = sA;
                red[wid][1][o] = sB;
            } else if (lane == 16) {
                red[wid][0][16] = Z0;
                red[wid][1][16] = Z1;
            }
            __syncthreads();   // B1

            if (t < 34) {
                const int nb = t / 17, k = t % 17;
                float s = red[0][nb][k];
                #pragma unroll
                for (int w = 1; w < NWAVES; ++w) s += red[w][nb][k];
                fin[nb][k] = s;
            }
            __syncthreads();   // B2

            // ---- squash both (redundant per thread; broadcast from LDS) ----
            {
                float rZA = (it == 0) ? (1.0f / 1152.0f) : (1.0f / fin[0][16]);
                float rZB = (it == 0) ? (1.0f / 1152.0f) : (1.0f / fin[1][16]);
                float n2A = 0.0f, n2B = 0.0f;
                #pragma unroll
                for (int o = 0; o < OUTCH; ++o) {
                    float sAo = fin[0][o] * rZA;
                    float sBo = fin[1][o] * rZB;
                    v0[o] = sAo; n2A = fmaf(sAo, sAo, n2A);
                    v1[o] = sBo; n2B = fmaf(sBo, sBo, n2B);
                }
                float scA = sqrtf(n2A) / (1.0f + n2A);
                float scB = sqrtf(n2B) / (1.0f + n2B);
                #pragma unroll
                for (int o = 0; o < OUTCH; ++o) { v0[o] *= scA; v1[o] *= scB; }
            }
            // fin/red reuse next iter is ordered by next iter's B1.
        }

        if (t == 0) {
            float* opA = OUT + ((size_t)(b0 + nA) * NCAPS + c) * OUTCH;
            float* opB = OUT + ((size_t)(b0 + nB_) * NCAPS + c) * OUTCH;
            #pragma unroll
            for (int o = 0; o < OUTCH; o += 4) {
                *reinterpret_cast<float4*>(opA + o) =
                    make_float4(v0[o], v0[o + 1], v0[o + 2], v0[o + 3]);
                *reinterpret_cast<float4*>(opB + o) =
                    make_float4(v1[o], v1[o + 1], v1[o + 2], v1[o + 3]);
            }
        }
        __syncthreads();   // separate red/fin use across pairs
    }
}

extern "C" void kernel_launch(void* const* d_in, const int* in_sizes, int n_in,
                              void* d_out, int out_size, void* d_ws, size_t ws_size,
                              hipStream_t stream) {
    const float* X = (const float*)d_in[0];            // (1152, 512, 8)
    const float* W = (const float*)d_in[1];            // (1152, 10, 16, 8)
    float* OUT     = (float*)d_out;                    // (512, 10, 16)
    dim3 grid(NCAPS * (NBATCH / NB));                  // 1280 workgroups, c-major
    caps_route_kernel<<<grid, dim3(TPB), 0, stream>>>(X, W, OUT);
}